// Round 1
// baseline (609.908 us; speedup 1.0000x reference)
//
#include <hip/hip_runtime.h>
#include <math.h>

#define NEGV (-1e30f)

constexpr int B = 512, T = 512, C = 128, L = 64;
constexpr int S = 2 * L + 1;      // 129
constexpr int BLANK = C - 1;      // 127

// ---------------------------------------------------------------------------
// K1: per-(b,t) row: logsumexp (for log-softmax) + argmax (greedy decode).
// One wave (64 lanes) per row of 128 floats; coalesced single pass.
// ---------------------------------------------------------------------------
__global__ __launch_bounds__(256) void rowstats_kernel(
    const float* __restrict__ logits, float* __restrict__ lse,
    int* __restrict__ pred) {
  int gtid = blockIdx.x * blockDim.x + threadIdx.x;
  int row = gtid >> 6;            // global wave id = row index
  int lane = threadIdx.x & 63;
  if (row >= B * T) return;
  const float* rp = logits + (size_t)row * C;
  float v1 = rp[lane];
  float v2 = rp[lane + 64];
  float v; int idx;
  if (v2 > v1) { v = v2; idx = lane + 64; } else { v = v1; idx = lane; }
  // wave argmax (first-index tie-break)
  for (int off = 32; off; off >>= 1) {
    float vo = __shfl_xor(v, off);
    int   io = __shfl_xor(idx, off);
    if (vo > v || (vo == v && io < idx)) { v = vo; idx = io; }
  }
  float sum = __expf(v1 - v) + __expf(v2 - v);
  for (int off = 32; off; off >>= 1) sum += __shfl_xor(sum, off);
  if (lane == 0) {
    lse[row] = v + __logf(sum);
    pred[row] = idx;
  }
}

// ---------------------------------------------------------------------------
// K2: CTC forward (alpha recursion). One block (128 threads) per sample.
// alpha[S] double-buffered in LDS; logits row staged to LDS each step.
// ---------------------------------------------------------------------------
__global__ __launch_bounds__(128) void ctc_kernel(
    const float* __restrict__ logits, const int* __restrict__ labels,
    const int* __restrict__ label_len, const int* __restrict__ logit_len,
    const float* __restrict__ lse, float* __restrict__ loss_out) {
  int b = blockIdx.x;
  int tid = threadIdx.x;
  __shared__ float lrow[C];
  __shared__ float alpha[2][S + 3];
  __shared__ int   extl[S];
  __shared__ unsigned char skipf[S];

  int ll = label_len[b];
  int tl = logit_len[b];
  const int* lab = labels + b * L;

  for (int s = tid; s < S; s += 128) {
    int e = (s & 1) ? lab[s >> 1] : BLANK;
    extl[s] = e;
    int sk = 0;
    if ((s & 1) && s >= 2) sk = (lab[s >> 1] != lab[(s >> 1) - 1]);
    skipf[s] = (unsigned char)sk;
  }
  __syncthreads();

  const float* lg = logits + (size_t)b * T * C;
  const float* lseb = lse + b * T;
  int cur = 0;
  for (int t = 0; t < tl; ++t) {
    lrow[tid] = lg[t * C + tid];
    __syncthreads();
    float lse_t = lseb[t];
    for (int s = tid; s < S; s += 128) {
      float lp = lrow[extl[s]] - lse_t;
      float nv;
      if (t == 0) {
        nv = (s < 2) ? lp : NEGV;
      } else {
        float a1 = alpha[cur][s];
        float a2 = (s >= 1) ? alpha[cur][s - 1] : NEGV;
        float a3 = (s >= 2 && skipf[s]) ? alpha[cur][s - 2] : NEGV;
        float m = fmaxf(a1, fmaxf(a2, a3));
        nv = m + __logf(__expf(a1 - m) + __expf(a2 - m) + __expf(a3 - m)) + lp;
      }
      alpha[cur ^ 1][s] = nv;
    }
    __syncthreads();
    cur ^= 1;
  }
  if (tid == 0) {
    float e1 = alpha[cur][2 * ll];
    float e2 = alpha[cur][2 * ll - 1];
    float m = fmaxf(e1, e2);
    loss_out[b] = -(m + __logf(__expf(e1 - m) + __expf(e2 - m)));
  }
}

// ---------------------------------------------------------------------------
// K3: greedy-collapse + Levenshtein DP. One wave per sample.
// Lane j owns DP column j+1 (label index j); column 0 is analytic (= i).
// new[j] = j + min( cummin_{k<=j}(cand[k]-k), i+1 )
// ---------------------------------------------------------------------------
__global__ __launch_bounds__(64) void editdist_kernel(
    const int* __restrict__ pred, const int* __restrict__ labels,
    const int* __restrict__ label_len, const int* __restrict__ logit_len,
    float* __restrict__ ler_out) {
  int b = blockIdx.x;
  int lane = threadIdx.x;           // 0..63
  int ll = label_len[b];
  int tl = logit_len[b];
  int lab = labels[b * L + lane];   // label for column lane+1
  int row = lane + 1;               // row0[col] = col
  int i = 0;                        // #dec elements consumed (= row[0])
  int prevc = -1;
  const int* pb = pred + b * T;
  for (int t = 0; t < tl; ++t) {
    int c = pb[t];
    bool keep = (c != BLANK) && (c != prevc);
    prevc = c;
    if (keep) {                     // wave-uniform branch
      int rowm1 = __shfl_up(row, 1);
      if (lane == 0) rowm1 = i;     // row[col-1] for col=1 is row[0] = i
      int cand = min(rowm1 + (c != lab ? 1 : 0), row + 1);
      int v = cand - (lane + 1);
      for (int off = 1; off < 64; off <<= 1) {   // inclusive min-scan
        int o = __shfl_up(v, off);
        if (lane >= off) v = min(v, o);
      }
      v = min(v, i + 1);            // chain from new[0] = i+1
      row = (lane + 1) + v;
      ++i;
    }
  }
  if (lane == ll - 1) ler_out[b] = (float)row / (float)ll;
}

// ---------------------------------------------------------------------------
// K4: deterministic final mean over B for loss and ler.
// ---------------------------------------------------------------------------
__global__ __launch_bounds__(512) void reduce_kernel(
    const float* __restrict__ loss_b, const float* __restrict__ ler_b,
    float* __restrict__ out) {
  __shared__ float sl[512];
  __shared__ float sr[512];
  int tid = threadIdx.x;
  sl[tid] = loss_b[tid];
  sr[tid] = ler_b[tid];
  __syncthreads();
  for (int off = 256; off; off >>= 1) {
    if (tid < off) { sl[tid] += sl[tid + off]; sr[tid] += sr[tid + off]; }
    __syncthreads();
  }
  if (tid == 0) {
    out[0] = sl[0] / (float)B;
    out[1] = sr[0] / (float)B;
  }
}

extern "C" void kernel_launch(void* const* d_in, const int* in_sizes, int n_in,
                              void* d_out, int out_size, void* d_ws, size_t ws_size,
                              hipStream_t stream) {
  const int*   labels    = (const int*)d_in[0];
  const float* logits    = (const float*)d_in[1];
  const int*   label_len = (const int*)d_in[2];
  const int*   logit_len = (const int*)d_in[3];
  float* out = (float*)d_out;

  char* ws = (char*)d_ws;
  float* lse    = (float*)ws;                          // B*T floats
  int*   pred   = (int*)(ws + (size_t)B * T * 4);      // B*T ints
  float* loss_b = (float*)(ws + (size_t)2 * B * T * 4);
  float* ler_b  = loss_b + B;

  rowstats_kernel<<<(B * T) / 4, 256, 0, stream>>>(logits, lse, pred);
  ctc_kernel<<<B, 128, 0, stream>>>(logits, labels, label_len, logit_len, lse, loss_b);
  editdist_kernel<<<B, 64, 0, stream>>>(pred, labels, label_len, logit_len, ler_b);
  reduce_kernel<<<1, 512, 0, stream>>>(loss_b, ler_b, out);
}

// Round 2
// 199.680 us; speedup vs baseline: 3.0544x; 3.0544x over previous
//
#include <hip/hip_runtime.h>
#include <hip/hip_fp16.h>
#include <math.h>
#include <limits.h>

#define NEGV (-1e30f)

constexpr int B = 512, T = 512, C = 128, L = 64;
constexpr int BLANK = C - 1;      // 127
constexpr int CH = 16;            // software-pipeline chunk (t-steps)
constexpr int NCH = T / CH;       // 32

// ---------------------------------------------------------------------------
// K1: per-(b,t) row. Computes log-sum-exp + argmax, then emits:
//   lp_lab[b,t,j] = logsoftmax(logits)[b,t,labels[b,j]]  (f16, 32 MB)
//   lp_bl [b,t]   = logsoftmax(logits)[b,t,BLANK]        (f32)
//   pred  [b,t]   = argmax_c logits[b,t,c]
// One wave per row; single coalesced pass over the 134 MB input.
// ---------------------------------------------------------------------------
__global__ __launch_bounds__(256) void rowstats_kernel(
    const float* __restrict__ logits, const int* __restrict__ labels,
    __half* __restrict__ lp_lab, float* __restrict__ lp_bl,
    int* __restrict__ pred) {
  int row = blockIdx.x * 4 + (threadIdx.x >> 6);
  int lane = threadIdx.x & 63;
  int b = row >> 9;  // T = 512
  const float* rp = logits + (size_t)row * C;
  float v1 = rp[lane];
  float v2 = rp[lane + 64];
  float v; int idx;
  if (v2 > v1) { v = v2; idx = lane + 64; } else { v = v1; idx = lane; }
  // butterfly argmax (first-index tie-break); all lanes converge
  for (int off = 1; off < 64; off <<= 1) {
    float vo = __shfl_xor(v, off);
    int   io = __shfl_xor(idx, off);
    if (vo > v || (vo == v && io < idx)) { v = vo; idx = io; }
  }
  float sum = __expf(v1 - v) + __expf(v2 - v);
  for (int off = 1; off < 64; off <<= 1) sum += __shfl_xor(sum, off);
  float lse = v + __logf(sum);
  // gather this sample's label log-probs via cross-lane permute
  int lab = labels[(size_t)b * L + lane];
  float g1 = __shfl(v1, lab & 63);
  float g2 = __shfl(v2, lab & 63);
  float gv = (lab < 64) ? g1 : g2;
  lp_lab[(size_t)row * 64 + lane] = __float2half(gv - lse);
  if (lane == 63) lp_bl[row] = v2 - lse;   // lane63's v2 = class 127 = blank
  if (lane == 0) pred[row] = idx;
}

// ---------------------------------------------------------------------------
// DPP inclusive min-scan over 64 lanes (rocPRIM pattern): row_shr 1/2/4/8,
// then row_bcast:15 (rows 1,3) and row_bcast:31 (rows 2,3). Invalid/masked
// lanes receive INT_MAX (min identity). ~6 VALU ops vs 6 ds_permutes.
// ---------------------------------------------------------------------------
__device__ __forceinline__ int scan_min64(int v) {
  int t;
  t = __builtin_amdgcn_update_dpp(INT_MAX, v, 0x111, 0xf, 0xf, false); v = min(v, t);
  t = __builtin_amdgcn_update_dpp(INT_MAX, v, 0x112, 0xf, 0xf, false); v = min(v, t);
  t = __builtin_amdgcn_update_dpp(INT_MAX, v, 0x114, 0xf, 0xf, false); v = min(v, t);
  t = __builtin_amdgcn_update_dpp(INT_MAX, v, 0x118, 0xf, 0xf, false); v = min(v, t);
  t = __builtin_amdgcn_update_dpp(INT_MAX, v, 0x142, 0xa, 0xf, false); v = min(v, t);
  t = __builtin_amdgcn_update_dpp(INT_MAX, v, 0x143, 0xc, 0xf, false); v = min(v, t);
  return v;
}

// one CTC alpha step; lane j holds states {2j, 2j+1}, aL = state 128 (replicated)
__device__ __forceinline__ void ctc_step(float lpl, float lpb, bool skip_ok, int lane,
                                         float& aE, float& aO, float& aL) {
  float pO  = __shfl_up(aO, 1);   // alpha[2j-1]
  float pE  = __shfl_up(aE, 1);   // alpha[2j-2]
  float o63 = __shfl(aO, 63);     // alpha[127] for state-128 update
  if (lane == 0) { pO = NEGV; pE = NEGV; }
  float a3 = skip_ok ? pE : NEGV;
  // even state 2j: a1=aE, a2=pO, a3=NEG (blank never skips) — 3-term like ref
  float mE = fmaxf(aE, pO);
  float nE = mE + __logf(__expf(aE - mE) + __expf(pO - mE) + __expf(NEGV - mE)) + lpb;
  // odd state 2j+1: a1=aO, a2=aE, a3=pE if allowed
  float mO = fmaxf(fmaxf(aO, aE), a3);
  float nO = mO + __logf(__expf(aO - mO) + __expf(aE - mO) + __expf(a3 - mO)) + lpl;
  // state 128 (blank): a1=aL, a2=alpha[127]
  float mL = fmaxf(aL, o63);
  float nL = mL + __logf(__expf(aL - mL) + __expf(o63 - mL) + __expf(NEGV - mL)) + lpb;
  aE = nE; aO = nO; aL = nL;
}

__device__ __forceinline__ void load_ctc(const __half* __restrict__ lpl,
                                         const float* __restrict__ lpb, int c,
                                         float (&bl)[CH], float (&bb)[CH]) {
#pragma unroll
  for (int k = 0; k < CH; ++k) {
    bl[k] = __half2float(lpl[(size_t)(c * CH + k) * 64]);
    bb[k] = lpb[c * CH + k];
  }
}

__device__ __forceinline__ void load_pred(const int* __restrict__ pb, int c,
                                          int (&bp)[CH]) {
#pragma unroll
  for (int k = 0; k < CH; ++k) bp[k] = pb[c * CH + k];
}

// ---------------------------------------------------------------------------
// K2 fused: blocks [0,B) = CTC alpha recursion (one wave/sample, no LDS, no
// barriers, 16-deep prefetch); blocks [B,2B) = greedy-collapse + Levenshtein
// (one wave/sample, DPP min-scan, 16-deep pred prefetch).
// ---------------------------------------------------------------------------
__global__ __launch_bounds__(64) void dp_kernel(
    const __half* __restrict__ lp_lab, const float* __restrict__ lp_bl,
    const int* __restrict__ pred, const int* __restrict__ labels,
    const int* __restrict__ label_len, const int* __restrict__ logit_len,
    float* __restrict__ loss_b, float* __restrict__ ler_b) {
  int lane = threadIdx.x;
  if (blockIdx.x < (unsigned)B) {
    // ---------------- CTC path ----------------
    int b = blockIdx.x;
    int tl = logit_len[b];
    int ll = label_len[b];
    int lab = labels[(size_t)b * L + lane];
    int labp = __shfl_up(lab, 1);
    bool skip_ok = (lane > 0) && (lab != labp);
    const __half* lpl = lp_lab + (size_t)b * T * 64 + lane;
    const float*  lpb = lp_bl + (size_t)b * T;

    float Al[CH], Ab[CH], Bl[CH], Bb[CH];
    load_ctc(lpl, lpb, 0, Al, Ab);
    load_ctc(lpl, lpb, 1, Bl, Bb);

    float aE = (lane == 0) ? Ab[0] : NEGV;   // s=0: blank at t=0
    float aO = (lane == 0) ? Al[0] : NEGV;   // s=1: labels[0] at t=0
    float aL = NEGV;
#pragma unroll
    for (int k = 1; k < CH; ++k)
      if (k < tl) ctc_step(Al[k], Ab[k], skip_ok, lane, aE, aO, aL);

    for (int c = 1; c < NCH; c += 2) {
      if (c + 1 < NCH) load_ctc(lpl, lpb, c + 1, Al, Ab);
#pragma unroll
      for (int k = 0; k < CH; ++k) {
        int t = c * CH + k;
        if (t < tl) ctc_step(Bl[k], Bb[k], skip_ok, lane, aE, aO, aL);
      }
      if (c + 2 < NCH) load_ctc(lpl, lpb, c + 2, Bl, Bb);
      if (c + 1 < NCH) {
#pragma unroll
        for (int k = 0; k < CH; ++k) {
          int t = (c + 1) * CH + k;
          if (t < tl) ctc_step(Al[k], Ab[k], skip_ok, lane, aE, aO, aL);
        }
      }
    }
    float e1 = (ll == L) ? aL : __shfl(aE, ll);   // alpha[2*ll]
    float e2 = __shfl(aO, ll - 1);                // alpha[2*ll-1]
    if (lane == 0) {
      float m = fmaxf(e1, e2);
      loss_b[b] = -(m + __logf(__expf(e1 - m) + __expf(e2 - m)));
    }
  } else {
    // ---------------- edit-distance path ----------------
    int b = blockIdx.x - B;
    int tl = logit_len[b];
    int ll = label_len[b];
    int lab = labels[(size_t)b * L + lane];   // lane j owns DP column j+1
    const int* pb = pred + (size_t)b * T;
    int row = lane + 1;                        // row0[col] = col
    int i = 0;                                 // kept chars consumed (= row[0])
    int prevc = -1;

    int Ap[CH], Bp[CH];
    load_pred(pb, 0, Ap);
    load_pred(pb, 1, Bp);

#pragma unroll
    for (int k = 0; k < CH; ++k) {
      if (k < tl) {
        int cc = Ap[k];
        bool keep = (cc != BLANK) && (cc != prevc);
        prevc = cc;
        if (keep) {
          int rowm1 = __shfl_up(row, 1);
          if (lane == 0) rowm1 = i;
          int v = min(rowm1 + (cc != lab), row + 1) - (lane + 1);
          v = scan_min64(v);
          row = (lane + 1) + min(v, i + 1);
          ++i;
        }
      }
    }
    for (int c = 1; c < NCH; c += 2) {
      if (c + 1 < NCH) load_pred(pb, c + 1, Ap);
#pragma unroll
      for (int k = 0; k < CH; ++k) {
        int t = c * CH + k;
        if (t < tl) {
          int cc = Bp[k];
          bool keep = (cc != BLANK) && (cc != prevc);
          prevc = cc;
          if (keep) {
            int rowm1 = __shfl_up(row, 1);
            if (lane == 0) rowm1 = i;
            int v = min(rowm1 + (cc != lab), row + 1) - (lane + 1);
            v = scan_min64(v);
            row = (lane + 1) + min(v, i + 1);
            ++i;
          }
        }
      }
      if (c + 2 < NCH) load_pred(pb, c + 2, Bp);
      if (c + 1 < NCH) {
#pragma unroll
        for (int k = 0; k < CH; ++k) {
          int t = (c + 1) * CH + k;
          if (t < tl) {
            int cc = Ap[k];
            bool keep = (cc != BLANK) && (cc != prevc);
            prevc = cc;
            if (keep) {
              int rowm1 = __shfl_up(row, 1);
              if (lane == 0) rowm1 = i;
              int v = min(rowm1 + (cc != lab), row + 1) - (lane + 1);
              v = scan_min64(v);
              row = (lane + 1) + min(v, i + 1);
              ++i;
            }
          }
        }
      }
    }
    if (lane == ll - 1) ler_b[b] = (float)row / (float)ll;
  }
}

// ---------------------------------------------------------------------------
// K3: deterministic final mean over B for loss and ler.
// ---------------------------------------------------------------------------
__global__ __launch_bounds__(512) void reduce_kernel(
    const float* __restrict__ loss_b, const float* __restrict__ ler_b,
    float* __restrict__ out) {
  __shared__ float sl[512];
  __shared__ float sr[512];
  int tid = threadIdx.x;
  sl[tid] = loss_b[tid];
  sr[tid] = ler_b[tid];
  __syncthreads();
  for (int off = 256; off; off >>= 1) {
    if (tid < off) { sl[tid] += sl[tid + off]; sr[tid] += sr[tid + off]; }
    __syncthreads();
  }
  if (tid == 0) {
    out[0] = sl[0] / (float)B;
    out[1] = sr[0] / (float)B;
  }
}

extern "C" void kernel_launch(void* const* d_in, const int* in_sizes, int n_in,
                              void* d_out, int out_size, void* d_ws, size_t ws_size,
                              hipStream_t stream) {
  const int*   labels    = (const int*)d_in[0];
  const float* logits    = (const float*)d_in[1];
  const int*   label_len = (const int*)d_in[2];
  const int*   logit_len = (const int*)d_in[3];
  float* out = (float*)d_out;

  char* ws = (char*)d_ws;
  __half* lp_lab = (__half*)ws;                                  // B*T*64 f16 = 32 MB
  float*  lp_bl  = (float*)(ws + (size_t)B * T * 64 * 2);        // B*T f32   =  1 MB
  int*    pred   = (int*)(ws + (size_t)B * T * 64 * 2 + (size_t)B * T * 4);
  float*  loss_b = (float*)(ws + (size_t)B * T * 64 * 2 + (size_t)2 * B * T * 4);
  float*  ler_b  = loss_b + B;

  rowstats_kernel<<<B * T / 4, 256, 0, stream>>>(logits, labels, lp_lab, lp_bl, pred);
  dp_kernel<<<2 * B, 64, 0, stream>>>(lp_lab, lp_bl, pred, labels, label_len,
                                      logit_len, loss_b, ler_b);
  reduce_kernel<<<1, 512, 0, stream>>>(loss_b, ler_b, out);
}

// Round 3
// 136.302 us; speedup vs baseline: 4.4747x; 1.4650x over previous
//
#include <hip/hip_runtime.h>
#include <hip/hip_fp16.h>
#include <math.h>
#include <limits.h>

#define NEGV (-1e30f)

constexpr int B = 512, T = 512, C = 128, L = 64;
constexpr int BLANK = C - 1;      // 127
constexpr int CH = 16;            // software-pipeline chunk (t-steps)
constexpr int NCH = T / CH;       // 32
constexpr float INV_LN2 = 1.44269504088896f;
constexpr float LN2 = 0.69314718055995f;

// ---------------------------------------------------------------------------
// DPP helpers. wave_shr1 (0x138): lane i gets lane i-1's value; lane 0 keeps
// `old`. Single VALU op (~4 cyc) vs ds_permute (~100 cyc).
// ---------------------------------------------------------------------------
__device__ __forceinline__ float dpp_shr1_f(float x, float old) {
  int r = __builtin_amdgcn_update_dpp(__float_as_int(old), __float_as_int(x),
                                      0x138, 0xf, 0xf, false);
  return __int_as_float(r);
}
__device__ __forceinline__ int dpp_shr1_i(int x, int old) {
  return __builtin_amdgcn_update_dpp(old, x, 0x138, 0xf, 0xf, false);
}

// inclusive min-scan over 64 lanes via DPP (row_shr 1/2/4/8 + row_bcast15/31)
__device__ __forceinline__ int scan_min64(int v) {
  int t;
  t = __builtin_amdgcn_update_dpp(INT_MAX, v, 0x111, 0xf, 0xf, false); v = min(v, t);
  t = __builtin_amdgcn_update_dpp(INT_MAX, v, 0x112, 0xf, 0xf, false); v = min(v, t);
  t = __builtin_amdgcn_update_dpp(INT_MAX, v, 0x114, 0xf, 0xf, false); v = min(v, t);
  t = __builtin_amdgcn_update_dpp(INT_MAX, v, 0x118, 0xf, 0xf, false); v = min(v, t);
  t = __builtin_amdgcn_update_dpp(INT_MAX, v, 0x142, 0xa, 0xf, false); v = min(v, t);
  t = __builtin_amdgcn_update_dpp(INT_MAX, v, 0x143, 0xc, 0xf, false); v = min(v, t);
  return v;
}

// ---------------------------------------------------------------------------
// K1: per-(b,t) row stats. Emits (log2 domain, pre-scaled by 1/ln2):
//   lp_lab[b,t,j] = log2softmax at labels[b,j] (f16), lp_bl[b,t] = at blank
//   (f32), pred[b,t] = argmax.
// ---------------------------------------------------------------------------
__global__ __launch_bounds__(256) void rowstats_kernel(
    const float* __restrict__ logits, const int* __restrict__ labels,
    __half* __restrict__ lp_lab, float* __restrict__ lp_bl,
    int* __restrict__ pred) {
  int row = blockIdx.x * 4 + (threadIdx.x >> 6);
  int lane = threadIdx.x & 63;
  int b = row >> 9;  // T = 512
  const float* rp = logits + (size_t)row * C;
  float v1 = rp[lane];
  float v2 = rp[lane + 64];
  float v; int idx;
  if (v2 > v1) { v = v2; idx = lane + 64; } else { v = v1; idx = lane; }
  for (int off = 1; off < 64; off <<= 1) {
    float vo = __shfl_xor(v, off);
    int   io = __shfl_xor(idx, off);
    if (vo > v || (vo == v && io < idx)) { v = vo; idx = io; }
  }
  float sum = __expf(v1 - v) + __expf(v2 - v);
  for (int off = 1; off < 64; off <<= 1) sum += __shfl_xor(sum, off);
  float lse = v + __logf(sum);
  int lab = labels[(size_t)b * L + lane];
  float g1 = __shfl(v1, lab & 63);
  float g2 = __shfl(v2, lab & 63);
  float gv = (lab < 64) ? g1 : g2;
  lp_lab[(size_t)row * 64 + lane] = __float2half((gv - lse) * INV_LN2);
  if (lane == 63) lp_bl[row] = (v2 - lse) * INV_LN2;  // class 127 = blank
  if (lane == 0) pred[row] = idx;
}

// ---------------------------------------------------------------------------
// one CTC alpha step, log2 domain. Lane j holds states {2j, 2j+1}; aL is the
// final blank state 128, meaningful only on lane 63 and only needed if ll==L.
// ---------------------------------------------------------------------------
__device__ __forceinline__ void ctc_step(float lpl, float lpb, bool skip_ok,
                                         bool needL, int lane,
                                         float& aE, float& aO, float& aL) {
  float pO = dpp_shr1_f(aO, NEGV);   // alpha[2j-1]
  float pE = dpp_shr1_f(aE, NEGV);   // alpha[2j-2]
  float a3 = skip_ok ? pE : NEGV;
  // even state 2j (blank): LSE2(aE, pO) + lpb
  float mE = fmaxf(aE, pO);
  float sE = __builtin_amdgcn_exp2f(aE - mE) + __builtin_amdgcn_exp2f(pO - mE);
  float nE = mE + __builtin_amdgcn_logf(sE) + lpb;
  // odd state 2j+1 (label j): LSE2(aO, aE, a3) + lpl
  float mO = fmaxf(fmaxf(aO, aE), a3);
  float sO = __builtin_amdgcn_exp2f(aO - mO) + __builtin_amdgcn_exp2f(aE - mO)
           + __builtin_amdgcn_exp2f(a3 - mO);
  float nO = mO + __builtin_amdgcn_logf(sO) + lpl;
  if (needL) {  // wave-uniform; uses own-lane aO (valid at lane 63)
    float mL = fmaxf(aL, aO);
    float sL = __builtin_amdgcn_exp2f(aL - mL) + __builtin_amdgcn_exp2f(aO - mL);
    aL = mL + __builtin_amdgcn_logf(sL) + lpb;
  }
  aE = nE; aO = nO;
}

__device__ __forceinline__ void load_ctc(const __half* __restrict__ lpl,
                                         const float* __restrict__ lpb, int c,
                                         float (&bl)[CH], float (&bb)[CH]) {
#pragma unroll
  for (int k = 0; k < CH; ++k) {
    bl[k] = __half2float(lpl[(size_t)(c * CH + k) * 64]);
    bb[k] = lpb[c * CH + k];
  }
}

__device__ __forceinline__ void load_pred(const int* __restrict__ pb, int c,
                                          int (&bp)[CH]) {
#pragma unroll
  for (int k = 0; k < CH; ++k) bp[k] = pb[c * CH + k];
}

__device__ __forceinline__ void edit_step(int cc, int lab, int lane,
                                          int& row, int& i, int& prevc) {
  bool keep = (cc != BLANK) && (cc != prevc);
  prevc = cc;
  if (keep) {                        // wave-uniform branch
    int rowm1 = dpp_shr1_i(row, i);  // row[col-1]; lane0 -> row[0] = i
    int v = min(rowm1 + (cc != lab), row + 1) - (lane + 1);
    v = scan_min64(v);
    row = (lane + 1) + min(v, i + 1);
    ++i;
  }
}

// ---------------------------------------------------------------------------
// K2 fused: blocks [0,B) = CTC (one wave/sample, DPP-only cross-lane);
// blocks [B,2B) = greedy-collapse + Levenshtein (DPP scan). launch_bounds
// (64,1): occupancy is structurally 1 wave/SIMD, so let VGPRs hold the
// 16-deep prefetch buffers.
// ---------------------------------------------------------------------------
__global__ __launch_bounds__(64, 1) void dp_kernel(
    const __half* __restrict__ lp_lab, const float* __restrict__ lp_bl,
    const int* __restrict__ pred, const int* __restrict__ labels,
    const int* __restrict__ label_len, const int* __restrict__ logit_len,
    float* __restrict__ loss_b, float* __restrict__ ler_b) {
  int lane = threadIdx.x;
  if (blockIdx.x < (unsigned)B) {
    // ---------------- CTC path ----------------
    int b = blockIdx.x;
    int tl = logit_len[b];
    int ll = label_len[b];
    bool needL = (ll == L);
    int lab = labels[(size_t)b * L + lane];
    int labp = __shfl_up(lab, 1);
    bool skip_ok = (lane > 0) && (lab != labp);
    const __half* lpl = lp_lab + (size_t)b * T * 64 + lane;
    const float*  lpb = lp_bl + (size_t)b * T;

    float Al[CH], Ab[CH], Bl[CH], Bb[CH];
    load_ctc(lpl, lpb, 0, Al, Ab);
    load_ctc(lpl, lpb, 1, Bl, Bb);

    float aE = (lane == 0) ? Ab[0] : NEGV;   // s=0: blank at t=0
    float aO = (lane == 0) ? Al[0] : NEGV;   // s=1: labels[0] at t=0
    float aL = NEGV;
#pragma unroll
    for (int k = 1; k < CH; ++k)
      if (k < tl) ctc_step(Al[k], Ab[k], skip_ok, needL, lane, aE, aO, aL);

    for (int c = 1; c < NCH; c += 2) {
      if (c + 1 < NCH) load_ctc(lpl, lpb, c + 1, Al, Ab);
#pragma unroll
      for (int k = 0; k < CH; ++k) {
        int t = c * CH + k;
        if (t < tl) ctc_step(Bl[k], Bb[k], skip_ok, needL, lane, aE, aO, aL);
      }
      if (c + 2 < NCH) load_ctc(lpl, lpb, c + 2, Bl, Bb);
      if (c + 1 < NCH) {
#pragma unroll
        for (int k = 0; k < CH; ++k) {
          int t = (c + 1) * CH + k;
          if (t < tl) ctc_step(Al[k], Ab[k], skip_ok, needL, lane, aE, aO, aL);
        }
      }
    }
    float e1 = needL ? __shfl(aL, 63) : __shfl(aE, ll);  // alpha[2*ll]
    float e2 = __shfl(aO, ll - 1);                       // alpha[2*ll-1]
    if (lane == 0) {
      float m = fmaxf(e1, e2);
      float r = m + __builtin_amdgcn_logf(__builtin_amdgcn_exp2f(e1 - m) +
                                          __builtin_amdgcn_exp2f(e2 - m));
      loss_b[b] = -r * LN2;
    }
  } else {
    // ---------------- edit-distance path ----------------
    int b = blockIdx.x - B;
    int tl = logit_len[b];
    int ll = label_len[b];
    int lab = labels[(size_t)b * L + lane];   // lane j owns DP column j+1
    const int* pb = pred + (size_t)b * T;
    int row = lane + 1;                        // row0[col] = col
    int i = 0;                                 // kept chars consumed (= row[0])
    int prevc = -1;

    int Ap[CH], Bp[CH];
    load_pred(pb, 0, Ap);
    load_pred(pb, 1, Bp);

#pragma unroll
    for (int k = 0; k < CH; ++k)
      if (k < tl) edit_step(Ap[k], lab, lane, row, i, prevc);

    for (int c = 1; c < NCH; c += 2) {
      if (c + 1 < NCH) load_pred(pb, c + 1, Ap);
#pragma unroll
      for (int k = 0; k < CH; ++k) {
        int t = c * CH + k;
        if (t < tl) edit_step(Bp[k], lab, lane, row, i, prevc);
      }
      if (c + 2 < NCH) load_pred(pb, c + 2, Bp);
      if (c + 1 < NCH) {
#pragma unroll
        for (int k = 0; k < CH; ++k) {
          int t = (c + 1) * CH + k;
          if (t < tl) edit_step(Ap[k], lab, lane, row, i, prevc);
        }
      }
    }
    if (lane == ll - 1) ler_b[b] = (float)row / (float)ll;
  }
}

// ---------------------------------------------------------------------------
// K3: deterministic final mean over B for loss and ler.
// ---------------------------------------------------------------------------
__global__ __launch_bounds__(512) void reduce_kernel(
    const float* __restrict__ loss_b, const float* __restrict__ ler_b,
    float* __restrict__ out) {
  __shared__ float sl[512];
  __shared__ float sr[512];
  int tid = threadIdx.x;
  sl[tid] = loss_b[tid];
  sr[tid] = ler_b[tid];
  __syncthreads();
  for (int off = 256; off; off >>= 1) {
    if (tid < off) { sl[tid] += sl[tid + off]; sr[tid] += sr[tid + off]; }
    __syncthreads();
  }
  if (tid == 0) {
    out[0] = sl[0] / (float)B;
    out[1] = sr[0] / (float)B;
  }
}

extern "C" void kernel_launch(void* const* d_in, const int* in_sizes, int n_in,
                              void* d_out, int out_size, void* d_ws, size_t ws_size,
                              hipStream_t stream) {
  const int*   labels    = (const int*)d_in[0];
  const float* logits    = (const float*)d_in[1];
  const int*   label_len = (const int*)d_in[2];
  const int*   logit_len = (const int*)d_in[3];
  float* out = (float*)d_out;

  char* ws = (char*)d_ws;
  __half* lp_lab = (__half*)ws;                                  // B*T*64 f16 = 32 MB
  float*  lp_bl  = (float*)(ws + (size_t)B * T * 64 * 2);        // B*T f32   =  1 MB
  int*    pred   = (int*)(ws + (size_t)B * T * 64 * 2 + (size_t)B * T * 4);
  float*  loss_b = (float*)(ws + (size_t)B * T * 64 * 2 + (size_t)2 * B * T * 4);
  float*  ler_b  = loss_b + B;

  rowstats_kernel<<<B * T / 4, 256, 0, stream>>>(logits, labels, lp_lab, lp_bl, pred);
  dp_kernel<<<2 * B, 64, 0, stream>>>(lp_lab, lp_bl, pred, labels, label_len,
                                      logit_len, loss_b, ler_b);
  reduce_kernel<<<1, 512, 0, stream>>>(loss_b, ler_b, out);
}

// Round 4
// 106.844 us; speedup vs baseline: 5.7084x; 1.2757x over previous
//
#include <hip/hip_runtime.h>
#include <hip/hip_fp16.h>
#include <math.h>
#include <limits.h>

#define NEGV (-1e30f)

constexpr int B = 512, T = 512, C = 128, L = 64;
constexpr int BLANK = C - 1;      // 127
constexpr int CH = 16;            // software-pipeline chunk (t-steps)
constexpr int NCH = T / CH;       // 32
constexpr float INV_LN2 = 1.44269504088896f;
constexpr float LN2 = 0.69314718055995f;

// ---------------------------------------------------------------------------
// DPP helpers (single VALU op each).
// ---------------------------------------------------------------------------
__device__ __forceinline__ float dpp_shr1_f(float x, float old) {
  int r = __builtin_amdgcn_update_dpp(__float_as_int(old), __float_as_int(x),
                                      0x138, 0xf, 0xf, false);  // wave_shr:1
  return __int_as_float(r);
}
__device__ __forceinline__ int dpp_shr1_i(int x, int old) {
  return __builtin_amdgcn_update_dpp(old, x, 0x138, 0xf, 0xf, false);
}

// inclusive 64-lane scans: row_shr 1/2/4/8 + row_bcast:15 (rows1,3) + :31 (2,3)
__device__ __forceinline__ int scan_min64(int v) {
  int t;
  t = __builtin_amdgcn_update_dpp(INT_MAX, v, 0x111, 0xf, 0xf, false); v = min(v, t);
  t = __builtin_amdgcn_update_dpp(INT_MAX, v, 0x112, 0xf, 0xf, false); v = min(v, t);
  t = __builtin_amdgcn_update_dpp(INT_MAX, v, 0x114, 0xf, 0xf, false); v = min(v, t);
  t = __builtin_amdgcn_update_dpp(INT_MAX, v, 0x118, 0xf, 0xf, false); v = min(v, t);
  t = __builtin_amdgcn_update_dpp(INT_MAX, v, 0x142, 0xa, 0xf, false); v = min(v, t);
  t = __builtin_amdgcn_update_dpp(INT_MAX, v, 0x143, 0xc, 0xf, false); v = min(v, t);
  return v;
}
__device__ __forceinline__ float scan_max64(float x) {
  const int NI = (int)0xff800000;  // -inf
  int t;
  t = __builtin_amdgcn_update_dpp(NI, __float_as_int(x), 0x111, 0xf, 0xf, false);
  x = fmaxf(x, __int_as_float(t));
  t = __builtin_amdgcn_update_dpp(NI, __float_as_int(x), 0x112, 0xf, 0xf, false);
  x = fmaxf(x, __int_as_float(t));
  t = __builtin_amdgcn_update_dpp(NI, __float_as_int(x), 0x114, 0xf, 0xf, false);
  x = fmaxf(x, __int_as_float(t));
  t = __builtin_amdgcn_update_dpp(NI, __float_as_int(x), 0x118, 0xf, 0xf, false);
  x = fmaxf(x, __int_as_float(t));
  t = __builtin_amdgcn_update_dpp(NI, __float_as_int(x), 0x142, 0xa, 0xf, false);
  x = fmaxf(x, __int_as_float(t));
  t = __builtin_amdgcn_update_dpp(NI, __float_as_int(x), 0x143, 0xc, 0xf, false);
  x = fmaxf(x, __int_as_float(t));
  return x;  // lane63 = wave max
}
__device__ __forceinline__ float scan_add64(float x) {
  int t;
  t = __builtin_amdgcn_update_dpp(0, __float_as_int(x), 0x111, 0xf, 0xf, false);
  x += __int_as_float(t);
  t = __builtin_amdgcn_update_dpp(0, __float_as_int(x), 0x112, 0xf, 0xf, false);
  x += __int_as_float(t);
  t = __builtin_amdgcn_update_dpp(0, __float_as_int(x), 0x114, 0xf, 0xf, false);
  x += __int_as_float(t);
  t = __builtin_amdgcn_update_dpp(0, __float_as_int(x), 0x118, 0xf, 0xf, false);
  x += __int_as_float(t);
  t = __builtin_amdgcn_update_dpp(0, __float_as_int(x), 0x142, 0xa, 0xf, false);
  x += __int_as_float(t);
  t = __builtin_amdgcn_update_dpp(0, __float_as_int(x), 0x143, 0xc, 0xf, false);
  x += __int_as_float(t);
  return x;  // lane63 = wave sum
}
__device__ __forceinline__ float readlane63(float x) {
  return __int_as_float(__builtin_amdgcn_readlane(__float_as_int(x), 63));
}

// ---------------------------------------------------------------------------
// K1: per-(b,t) row stats. DPP scans (VALU) instead of shfl butterflies.
// Emits log2-domain: lp_lab[b,t,j] (f16), lp_bl[b,t] (f32), pred[b,t].
// Argmax tie-break on raw f32 == reference bit-exact.
// ---------------------------------------------------------------------------
__global__ __launch_bounds__(256) void rowstats_kernel(
    const float* __restrict__ logits, const int* __restrict__ labels,
    __half* __restrict__ lp_lab, float* __restrict__ lp_bl,
    int* __restrict__ pred) {
  int row = blockIdx.x * 4 + (threadIdx.x >> 6);
  int lane = threadIdx.x & 63;
  int b = row >> 9;  // T = 512
  const float* rp = logits + (size_t)row * C;
  float v1 = rp[lane];
  float v2 = rp[lane + 64];
  float m = readlane63(scan_max64(fmaxf(v1, v2)));   // raw-domain max
  // argmax with first-index tie-break (class of v1 = lane, v2 = lane+64)
  unsigned long long b1 = __ballot(v1 == m);
  unsigned long long b2 = __ballot(v2 == m);
  int idx = b1 ? (__ffsll(b1) - 1) : (64 + __ffsll(b2) - 1);
  float s = __builtin_amdgcn_exp2f((v1 - m) * INV_LN2) +
            __builtin_amdgcn_exp2f((v2 - m) * INV_LN2);
  float l2t = __builtin_amdgcn_logf(readlane63(scan_add64(s)));  // log2(sum)
  // gather this sample's label log2-probs
  int lab = labels[(size_t)b * L + lane];
  float g1 = __shfl(v1, lab & 63);
  float g2 = __shfl(v2, lab & 63);
  float gv = (lab < 64) ? g1 : g2;
  lp_lab[(size_t)row * 64 + lane] = __float2half((gv - m) * INV_LN2 - l2t);
  if (lane == 63) lp_bl[row] = (v2 - m) * INV_LN2 - l2t;  // class 127 = blank
  if (lane == 0) pred[row] = idx;
}

// ---------------------------------------------------------------------------
// CTC alpha step, log2 domain. Lane j holds states {2j, 2j+1}; aL = state 128,
// meaningful on lane 63 only, updated only when ll == L (wave-uniform).
// ---------------------------------------------------------------------------
__device__ __forceinline__ float lse2_2(float a, float b) {
  float m = fmaxf(a, b);
  float d = fminf(a, b) - m;
  return m + __builtin_amdgcn_logf(1.0f + __builtin_amdgcn_exp2f(d));
}
__device__ __forceinline__ void ctc_step(float lpl, float lpb, bool skip_ok,
                                         bool needL, int lane,
                                         float& aE, float& aO, float& aL) {
  float pO = dpp_shr1_f(aO, NEGV);   // alpha[2j-1]
  float pE = dpp_shr1_f(aE, NEGV);   // alpha[2j-2]
  float a3 = skip_ok ? pE : NEGV;
  float nE = lse2_2(aE, pO) + lpb;   // even state 2j (blank)
  float mO = fmaxf(fmaxf(aO, aE), a3);
  float sO = __builtin_amdgcn_exp2f(aO - mO) + __builtin_amdgcn_exp2f(aE - mO)
           + __builtin_amdgcn_exp2f(a3 - mO);
  float nO = mO + __builtin_amdgcn_logf(sO) + lpl;  // odd state 2j+1
  if (needL) aL = lse2_2(aL, aO) + lpb;             // state 128 (tail blank)
  aE = nE; aO = nO;
}

__device__ __forceinline__ void load_ctc(const __half* __restrict__ lpl,
                                         const float* __restrict__ lpb, int c,
                                         float (&bl)[CH], float (&bb)[CH]) {
#pragma unroll
  for (int k = 0; k < CH; ++k) {
    bl[k] = __half2float(lpl[(size_t)(c * CH + k) * 64]);
    bb[k] = lpb[c * CH + k];
  }
}
__device__ __forceinline__ void load_pred(const int* __restrict__ pb, int c,
                                          int (&bp)[CH]) {
#pragma unroll
  for (int k = 0; k < CH; ++k) bp[k] = pb[c * CH + k];
}

__device__ __forceinline__ void edit_step(int cc, int lab, int lane,
                                          int& row, int& i, int& prevc) {
  bool keep = (cc != BLANK) && (cc != prevc);
  prevc = cc;
  if (keep) {                        // wave-uniform branch
    int rowm1 = dpp_shr1_i(row, i);  // row[col-1]; lane0 -> row[0] = i
    int v = min(rowm1 + (cc != lab), row + 1) - (lane + 1);
    v = scan_min64(v);
    row = (lane + 1) + min(v, i + 1);
    ++i;
  }
}

// ---------------------------------------------------------------------------
// K2 fused: blocks [0,B) = CTC; blocks [B,2B) = greedy + Levenshtein.
// sched_barrier(0) after every prefetch block pins load ISSUE before the
// compute region (waits still happen only at first use -> loads in flight).
// ---------------------------------------------------------------------------
__global__ __launch_bounds__(64, 1) void dp_kernel(
    const __half* __restrict__ lp_lab, const float* __restrict__ lp_bl,
    const int* __restrict__ pred, const int* __restrict__ labels,
    const int* __restrict__ label_len, const int* __restrict__ logit_len,
    float* __restrict__ loss_b, float* __restrict__ ler_b) {
  int lane = threadIdx.x;
  if (blockIdx.x < (unsigned)B) {
    // ---------------- CTC path ----------------
    int b = blockIdx.x;
    int tl = logit_len[b];
    int ll = label_len[b];
    bool needL = (ll == L);
    int lab = labels[(size_t)b * L + lane];
    int labp = __shfl_up(lab, 1);
    bool skip_ok = (lane > 0) && (lab != labp);
    const __half* lpl = lp_lab + (size_t)b * T * 64 + lane;
    const float*  lpb = lp_bl + (size_t)b * T;

    float Al[CH], Ab[CH], Bl[CH], Bb[CH];
    load_ctc(lpl, lpb, 0, Al, Ab);
    load_ctc(lpl, lpb, 1, Bl, Bb);
    __builtin_amdgcn_sched_barrier(0);

    float aE = (lane == 0) ? Ab[0] : NEGV;   // s=0: blank at t=0
    float aO = (lane == 0) ? Al[0] : NEGV;   // s=1: labels[0] at t=0
    float aL = NEGV;
    if (CH <= tl) {
#pragma unroll
      for (int k = 1; k < CH; ++k)
        ctc_step(Al[k], Ab[k], skip_ok, needL, lane, aE, aO, aL);
    } else {
#pragma unroll
      for (int k = 1; k < CH; ++k)
        if (k < tl) ctc_step(Al[k], Ab[k], skip_ok, needL, lane, aE, aO, aL);
    }

    for (int c = 1; c < NCH; c += 2) {
      if (c + 1 < NCH) load_ctc(lpl, lpb, c + 1, Al, Ab);
      __builtin_amdgcn_sched_barrier(0);
      if ((c + 1) * CH <= tl) {
#pragma unroll
        for (int k = 0; k < CH; ++k)
          ctc_step(Bl[k], Bb[k], skip_ok, needL, lane, aE, aO, aL);
      } else {
#pragma unroll
        for (int k = 0; k < CH; ++k) {
          int t = c * CH + k;
          if (t < tl) ctc_step(Bl[k], Bb[k], skip_ok, needL, lane, aE, aO, aL);
        }
      }
      if (c + 2 < NCH) load_ctc(lpl, lpb, c + 2, Bl, Bb);
      __builtin_amdgcn_sched_barrier(0);
      if (c + 1 < NCH) {
        if ((c + 2) * CH <= tl) {
#pragma unroll
          for (int k = 0; k < CH; ++k)
            ctc_step(Al[k], Ab[k], skip_ok, needL, lane, aE, aO, aL);
        } else {
#pragma unroll
          for (int k = 0; k < CH; ++k) {
            int t = (c + 1) * CH + k;
            if (t < tl) ctc_step(Al[k], Ab[k], skip_ok, needL, lane, aE, aO, aL);
          }
        }
      }
    }
    float e1 = needL ? __shfl(aL, 63) : __shfl(aE, ll);  // alpha[2*ll]
    float e2 = __shfl(aO, ll - 1);                       // alpha[2*ll-1]
    if (lane == 0) {
      float m = fmaxf(e1, e2);
      float r = m + __builtin_amdgcn_logf(__builtin_amdgcn_exp2f(e1 - m) +
                                          __builtin_amdgcn_exp2f(e2 - m));
      loss_b[b] = -r * LN2;
    }
  } else {
    // ---------------- edit-distance path ----------------
    int b = blockIdx.x - B;
    int tl = logit_len[b];
    int ll = label_len[b];
    int lab = labels[(size_t)b * L + lane];   // lane j owns DP column j+1
    const int* pb = pred + (size_t)b * T;
    int row = lane + 1;                        // row0[col] = col
    int i = 0;                                 // kept chars consumed (= row[0])
    int prevc = -1;

    int Ap[CH], Bp[CH];
    load_pred(pb, 0, Ap);
    load_pred(pb, 1, Bp);
    __builtin_amdgcn_sched_barrier(0);

    if (CH <= tl) {
#pragma unroll
      for (int k = 0; k < CH; ++k) edit_step(Ap[k], lab, lane, row, i, prevc);
    } else {
#pragma unroll
      for (int k = 0; k < CH; ++k)
        if (k < tl) edit_step(Ap[k], lab, lane, row, i, prevc);
    }

    for (int c = 1; c < NCH; c += 2) {
      if (c + 1 < NCH) load_pred(pb, c + 1, Ap);
      __builtin_amdgcn_sched_barrier(0);
      if ((c + 1) * CH <= tl) {
#pragma unroll
        for (int k = 0; k < CH; ++k) edit_step(Bp[k], lab, lane, row, i, prevc);
      } else {
#pragma unroll
        for (int k = 0; k < CH; ++k) {
          int t = c * CH + k;
          if (t < tl) edit_step(Bp[k], lab, lane, row, i, prevc);
        }
      }
      if (c + 2 < NCH) load_pred(pb, c + 2, Bp);
      __builtin_amdgcn_sched_barrier(0);
      if (c + 1 < NCH) {
        if ((c + 2) * CH <= tl) {
#pragma unroll
          for (int k = 0; k < CH; ++k) edit_step(Ap[k], lab, lane, row, i, prevc);
        } else {
#pragma unroll
          for (int k = 0; k < CH; ++k) {
            int t = (c + 1) * CH + k;
            if (t < tl) edit_step(Ap[k], lab, lane, row, i, prevc);
          }
        }
      }
    }
    if (lane == ll - 1) ler_b[b] = (float)row / (float)ll;
  }
}

// ---------------------------------------------------------------------------
// K3: deterministic final mean over B for loss and ler.
// ---------------------------------------------------------------------------
__global__ __launch_bounds__(512) void reduce_kernel(
    const float* __restrict__ loss_b, const float* __restrict__ ler_b,
    float* __restrict__ out) {
  __shared__ float sl[512];
  __shared__ float sr[512];
  int tid = threadIdx.x;
  sl[tid] = loss_b[tid];
  sr[tid] = ler_b[tid];
  __syncthreads();
  for (int off = 256; off; off >>= 1) {
    if (tid < off) { sl[tid] += sl[tid + off]; sr[tid] += sr[tid + off]; }
    __syncthreads();
  }
  if (tid == 0) {
    out[0] = sl[0] / (float)B;
    out[1] = sr[0] / (float)B;
  }
}

extern "C" void kernel_launch(void* const* d_in, const int* in_sizes, int n_in,
                              void* d_out, int out_size, void* d_ws, size_t ws_size,
                              hipStream_t stream) {
  const int*   labels    = (const int*)d_in[0];
  const float* logits    = (const float*)d_in[1];
  const int*   label_len = (const int*)d_in[2];
  const int*   logit_len = (const int*)d_in[3];
  float* out = (float*)d_out;

  char* ws = (char*)d_ws;
  __half* lp_lab = (__half*)ws;                                  // B*T*64 f16 = 32 MB
  float*  lp_bl  = (float*)(ws + (size_t)B * T * 64 * 2);        // B*T f32   =  1 MB
  int*    pred   = (int*)(ws + (size_t)B * T * 64 * 2 + (size_t)B * T * 4);
  float*  loss_b = (float*)(ws + (size_t)B * T * 64 * 2 + (size_t)2 * B * T * 4);
  float*  ler_b  = loss_b + B;

  rowstats_kernel<<<B * T / 4, 256, 0, stream>>>(logits, labels, lp_lab, lp_bl, pred);
  dp_kernel<<<2 * B, 64, 0, stream>>>(lp_lab, lp_bl, pred, labels, label_len,
                                      logit_len, loss_b, ler_b);
  reduce_kernel<<<1, 512, 0, stream>>>(loss_b, ler_b, out);
}